// Round 1
// baseline (886.074 us; speedup 1.0000x reference)
//
#include <hip/hip_runtime.h>
#include <math.h>

#define NA 8192
#define NB 131072
#define NG 16
#define NSHARD 16
#define PART_STRIDE 36

// workspace layout (in floats)
#define OFF_V    0u          // 3*16*1024   = 49152
#define OFF_AGG  65536u      // 3*8192*32   = 786432
#define OFF_QKV  851968u     // 3*8192*32   = 786432
#define OFF_PART 1638400u    // 16*8192*36  = 4718592   (total ~25.4 MB)

// V[h][g][n] = sum_c state[g,c]*We[h,32+c,n] + be[h,n]   (n = i*32+j)
__global__ __launch_bounds__(256) void prep_v(const float* __restrict__ state,
    const float* __restrict__ We, const float* __restrict__ be, float* __restrict__ V)
{
    int h = blockIdx.x >> 4, g = blockIdx.x & 15;
    const float* st = state + g * 32;
    const float* W  = We + ((size_t)h * 64 + 32) * 1024;
    const float* bb = be + (size_t)h * 1024;
    int n = threadIdx.x * 4;
    float4 acc = *(const float4*)(bb + n);
    for (int c = 0; c < 32; ++c) {
        float s = st[c];
        const float4 w = *(const float4*)(W + c * 1024 + n);
        acc.x += s * w.x; acc.y += s * w.y; acc.z += s * w.z; acc.w += s * w.w;
    }
    *(float4*)(V + ((size_t)h * 16 + g) * 1024 + n) = acc;
}

// Fused edge message + segment-sum.
// Block: 32 edges, thread = (e_loc = tid>>3, it = tid&7 -> i = it*4+ii).
// msg[e,i] = sum_s cf[s,e] * (sum_j Wslice[s][i*32+j] * neigh[e,j])
//   s<32: cf=bond[e,s], slice = We[h][s];  s>=32: cf=(g(e)==gmin+s-32), slice = V[h][g]
__global__ __launch_bounds__(256) void msg_kernel(
    const float* __restrict__ atom, const float* __restrict__ bond,
    const float* __restrict__ We, const int* __restrict__ pair,
    const int* __restrict__ bg, const float* __restrict__ V,
    float* __restrict__ agg)
{
    __shared__ float Ws[8][32][36];   // [slice][j][i] transposed, padded: conflict-free
    __shared__ float cf[48][32];
    __shared__ int gmm[2];
    const int tid = threadIdx.x;
    const int h  = blockIdx.y;
    const int e0 = blockIdx.x * 32;
    const int el = tid >> 3;
    const int it = tid & 7;
    if (tid == 0) { gmm[0] = bg[e0]; gmm[1] = bg[e0 + 31]; }
    __syncthreads();
    const int gmin = gmm[0];
    const int ns = 32 + (gmm[1] - gmin) + 1;   // bond_graph sorted -> usually 33
    for (int x = tid; x < ns * 32; x += 256) {
        int s = x >> 5, e = x & 31;
        float c;
        if (s < 32) c = bond[(size_t)(e0 + e) * 32 + s];
        else        c = (bg[e0 + e] == gmin + (s - 32)) ? 1.f : 0.f;
        cf[s][e] = c;
    }
    // neighbor row in registers (atom[pair[e,1]])
    float nr[32];
    const int ge  = e0 + el;
    const int srcA = pair[2 * ge + 1];
    {
        const float* ap = atom + (size_t)srcA * 32;
        #pragma unroll
        for (int q = 0; q < 8; ++q) {
            float4 v = *(const float4*)(ap + q * 4);
            nr[q*4+0] = v.x; nr[q*4+1] = v.y; nr[q*4+2] = v.z; nr[q*4+3] = v.w;
        }
    }
    float macc[4] = {0.f, 0.f, 0.f, 0.f};
    for (int s0 = 0; s0 < ns; s0 += 8) {
        const int cnt = min(8, ns - s0);
        __syncthreads();
        for (int sl = 0; sl < cnt; ++sl) {
            int s = s0 + sl;
            const float* srcp = (s < 32) ? (We + ((size_t)h * 64 + s) * 1024)
                                         : (V + ((size_t)h * 16 + (gmin + s - 32)) * 1024);
            int n0 = tid * 4;
            float4 v = *(const float4*)(srcp + n0);
            int i = n0 >> 5, j = n0 & 31;       // n0..n0+3 stay within one i-row
            Ws[sl][j+0][i] = v.x; Ws[sl][j+1][i] = v.y;
            Ws[sl][j+2][i] = v.z; Ws[sl][j+3][i] = v.w;
        }
        __syncthreads();
        for (int sl = 0; sl < cnt; ++sl) {
            float c = cf[s0 + sl][el];
            float d0 = 0.f, d1 = 0.f, d2 = 0.f, d3 = 0.f;
            #pragma unroll
            for (int j = 0; j < 32; ++j) {
                const float4 w = *(const float4*)(&Ws[sl][j][it * 4]);
                float nv = nr[j];
                d0 += w.x * nv; d1 += w.y * nv; d2 += w.z * nv; d3 += w.w * nv;
            }
            macc[0] += c * d0; macc[1] += c * d1; macc[2] += c * d2; macc[3] += c * d3;
        }
    }
    const int a = pair[2 * ge];   // destination atom (pair[:,0])
    float* dst = agg + ((size_t)h * NA + a) * 32 + it * 4;
    atomicAdd(dst + 0, macc[0]);
    atomicAdd(dst + 1, macc[1]);
    atomicAdd(dst + 2, macc[2]);
    atomicAdd(dst + 3, macc[3]);
}

// GRU (STEPS=1): qkv[h][a][i]
__global__ __launch_bounds__(256) void gru_kernel(
    const float* __restrict__ atom, const float* __restrict__ agg,
    const float* __restrict__ Wx, const float* __restrict__ Wh,
    const float* __restrict__ bx, const float* __restrict__ bh,
    float* __restrict__ qkv)
{
    __shared__ float ag[8][32], at[8][32];
    const int tid = threadIdx.x;
    const int r = tid >> 5, i = tid & 31;
    const int ha = blockIdx.x * 8 + r;       // ha = h*8192 + a
    const int h = ha >> 13;
    const int a = ha & 8191;
    ag[r][i] = agg[(size_t)ha * 32 + i];
    at[r][i] = atom[(size_t)a * 32 + i];
    __syncthreads();
    const float* wx = Wx + (size_t)h * 32 * 96;
    const float* wh = Wh + (size_t)h * 32 * 96;
    float x0 = bx[h*96 + i], x1 = bx[h*96 + 32 + i], x2 = bx[h*96 + 64 + i];
    float g0 = bh[h*96 + i], g1 = bh[h*96 + 32 + i], g2 = bh[h*96 + 64 + i];
    #pragma unroll 4
    for (int c = 0; c < 32; ++c) {
        float av = ag[r][c], hv = at[r][c];
        x0 += av * wx[c*96 + i]; x1 += av * wx[c*96 + 32 + i]; x2 += av * wx[c*96 + 64 + i];
        g0 += hv * wh[c*96 + i]; g1 += hv * wh[c*96 + 32 + i]; g2 += hv * wh[c*96 + 64 + i];
    }
    float z  = 1.f / (1.f + __expf(-(x0 + g0)));
    float rr = 1.f / (1.f + __expf(-(x1 + g1)));
    float hc = tanhf(x2 + rr * g2);
    float hn = z * at[r][i] + (1.f - z) * hc;
    qkv[(size_t)ha * 32 + i] = hn;
}

// Flash attention phase 1: each thread owns one q row, processes one k-shard of 512.
__global__ __launch_bounds__(128) void attn_kernel(
    const float* __restrict__ qkv, float* __restrict__ part)
{
    __shared__ float Kt[32][32], Vt[32][32];
    const int tid = threadIdx.x;
    const int q = blockIdx.x * 128 + tid;
    const int sh = blockIdx.y;
    const float* Q  = qkv;
    const float* K  = qkv + (size_t)NA * 32;
    const float* Vv = qkv + (size_t)2 * NA * 32;
    float qr[32];
    #pragma unroll
    for (int w = 0; w < 8; ++w) {
        float4 v = *(const float4*)(Q + (size_t)q * 32 + w * 4);
        qr[w*4] = v.x; qr[w*4+1] = v.y; qr[w*4+2] = v.z; qr[w*4+3] = v.w;
    }
    float m = -INFINITY, l = 0.f;
    float acc[32];
    #pragma unroll
    for (int c = 0; c < 32; ++c) acc[c] = 0.f;
    const float scale = 0.1767766952966369f;   // 1/sqrt(32)
    for (int kt = 0; kt < 512; kt += 32) {
        const int k0 = sh * 512 + kt;
        __syncthreads();
        {   // stage 32 K rows + 32 V rows (1024 f32 each)
            int x = tid * 8;
            *(float4*)(&Kt[0][0] + x)     = *(const float4*)(K + (size_t)k0 * 32 + x);
            *(float4*)(&Kt[0][0] + x + 4) = *(const float4*)(K + (size_t)k0 * 32 + x + 4);
            *(float4*)(&Vt[0][0] + x)     = *(const float4*)(Vv + (size_t)k0 * 32 + x);
            *(float4*)(&Vt[0][0] + x + 4) = *(const float4*)(Vv + (size_t)k0 * 32 + x + 4);
        }
        __syncthreads();
        float s[32];
        #pragma unroll
        for (int kk = 0; kk < 32; ++kk) {
            float d = 0.f;
            #pragma unroll
            for (int c8 = 0; c8 < 8; ++c8) {
                const float4 kv = *(const float4*)(&Kt[kk][c8 * 4]);
                d += qr[c8*4] * kv.x + qr[c8*4+1] * kv.y + qr[c8*4+2] * kv.z + qr[c8*4+3] * kv.w;
            }
            s[kk] = d * scale;
        }
        float tmax = s[0];
        #pragma unroll
        for (int kk = 1; kk < 32; ++kk) tmax = fmaxf(tmax, s[kk]);
        float mn = fmaxf(m, tmax);
        float al = __expf(m - mn);   // m=-inf -> 0
        l *= al;
        #pragma unroll
        for (int c = 0; c < 32; ++c) acc[c] *= al;
        #pragma unroll
        for (int kk = 0; kk < 32; ++kk) {
            float p = __expf(s[kk] - mn);
            l += p;
            #pragma unroll
            for (int c8 = 0; c8 < 8; ++c8) {
                const float4 vv = *(const float4*)(&Vt[kk][c8 * 4]);
                acc[c8*4]   += p * vv.x; acc[c8*4+1] += p * vv.y;
                acc[c8*4+2] += p * vv.z; acc[c8*4+3] += p * vv.w;
            }
        }
        m = mn;
    }
    float* pp = part + ((size_t)sh * NA + q) * PART_STRIDE;
    #pragma unroll
    for (int c = 0; c < 32; ++c) pp[c] = acc[c];
    pp[32] = m; pp[33] = l;
}

// Merge the 16 shard partials per q row.
__global__ __launch_bounds__(256) void merge_kernel(const float* __restrict__ part,
                                                    float* __restrict__ out)
{
    const int tid = threadIdx.x;
    const int r = tid >> 5, c = tid & 31;
    const int q = blockIdx.x * 8 + r;
    float ms = -INFINITY;
    #pragma unroll
    for (int sh = 0; sh < NSHARD; ++sh)
        ms = fmaxf(ms, part[((size_t)sh * NA + q) * PART_STRIDE + 32]);
    float den = 0.f, num = 0.f;
    #pragma unroll
    for (int sh = 0; sh < NSHARD; ++sh) {
        const float* pp = part + ((size_t)sh * NA + q) * PART_STRIDE;
        float w = __expf(pp[32] - ms);
        den += w * pp[33];
        num += w * pp[c];
    }
    out[(size_t)q * 32 + c] = num / den;
}

extern "C" void kernel_launch(void* const* d_in, const int* in_sizes, int n_in,
                              void* d_out, int out_size, void* d_ws, size_t ws_size,
                              hipStream_t stream)
{
    const float* atom  = (const float*)d_in[0];
    const float* bond  = (const float*)d_in[1];
    const float* state = (const float*)d_in[2];
    const float* We    = (const float*)d_in[3];
    const float* be    = (const float*)d_in[4];
    const float* Wx    = (const float*)d_in[5];
    const float* Wh    = (const float*)d_in[6];
    const float* bx    = (const float*)d_in[7];
    const float* bh    = (const float*)d_in[8];
    const int*   pair  = (const int*)d_in[9];    // int32 per harness convention
    const int*   bg    = (const int*)d_in[11];   // bond_graph_indices (sorted)
    float* ws   = (float*)d_ws;
    float* V    = ws + OFF_V;
    float* agg  = ws + OFF_AGG;
    float* qkv  = ws + OFF_QKV;
    float* part = ws + OFF_PART;
    float* out  = (float*)d_out;

    hipMemsetAsync(agg, 0, (size_t)3 * NA * 32 * sizeof(float), stream);
    prep_v<<<48, 256, 0, stream>>>(state, We, be, V);
    msg_kernel<<<dim3(NB / 32, 3), 256, 0, stream>>>(atom, bond, We, pair, bg, V, agg);
    gru_kernel<<<3 * NA / 8, 256, 0, stream>>>(atom, agg, Wx, Wh, bx, bh, qkv);
    attn_kernel<<<dim3(NA / 128, NSHARD), 128, 0, stream>>>(qkv, part);
    merge_kernel<<<NA / 8, 256, 0, stream>>>(part, out);
}

// Round 2
// 440.984 us; speedup vs baseline: 2.0093x; 2.0093x over previous
//
#include <hip/hip_runtime.h>
#include <hip/hip_bf16.h>
#include <math.h>

#define NA 8192
#define NB 131072
#define NG 16
#define NSHARD 16
#define PART_STRIDE 34

// workspace layout (float offsets)
#define OFF_BH   0u          // 3*32*1024 bf16  = 49152 floats
#define OFF_AGG  65536u      // 3*8192*32 f32   = 786432
#define OFF_QKV  851968u     // 3*8192*32 f32   = 786432
#define OFF_PART 1638400u    // 16*8192*34 f32  = 4456448
#define OFF_VB   6094848u    // 3*16*1024 bf16  = 24576 floats  (end ~24.5 MB)

typedef __attribute__((ext_vector_type(8))) short short8;
typedef __attribute__((ext_vector_type(4))) float f4;

__device__ inline unsigned short bfb(float x) {
    __hip_bfloat16 b = __float2bfloat16(x);   // RNE, HW cvt on gfx950
    return reinterpret_cast<unsigned short&>(b);
}

// Bh[h][c][n*32+j] = bf16(We[h][c][n*32+j]), c<32 (bond channels only)
__global__ __launch_bounds__(256) void prep_bh(const float* __restrict__ We,
                                               unsigned short* __restrict__ Bh)
{
    int idx = blockIdx.x * 256 + threadIdx.x;      // float4 index, 24576 total
    int hc = idx >> 8;                             // 256 float4 per (h,c) row
    int h = hc >> 5, c = hc & 31;
    int n4 = (idx & 255) * 4;
    const float4 v = *(const float4*)(We + ((size_t)(h * 64 + c)) * 1024 + n4);
    unsigned short* d = Bh + (size_t)hc * 1024 + n4;
    d[0] = bfb(v.x); d[1] = bfb(v.y); d[2] = bfb(v.z); d[3] = bfb(v.w);
}

// Vb[h][g][n] = bf16( sum_c state[g,c]*We[h,32+c,n] + be[h,n] )
__global__ __launch_bounds__(256) void prep_v(const float* __restrict__ state,
    const float* __restrict__ We, const float* __restrict__ be,
    unsigned short* __restrict__ Vb)
{
    int h = blockIdx.x >> 4, g = blockIdx.x & 15;
    const float* st = state + g * 32;
    const float* W  = We + ((size_t)h * 64 + 32) * 1024;
    const float* bb = be + (size_t)h * 1024;
    int n = threadIdx.x * 4;
    float4 acc = *(const float4*)(bb + n);
    for (int c = 0; c < 32; ++c) {
        float s = st[c];
        const float4 w = *(const float4*)(W + c * 1024 + n);
        acc.x += s * w.x; acc.y += s * w.y; acc.z += s * w.z; acc.w += s * w.w;
    }
    unsigned short* d = Vb + ((size_t)h * 16 + g) * 1024 + n;
    d[0] = bfb(acc.x); d[1] = bfb(acc.y); d[2] = bfb(acc.z); d[3] = bfb(acc.w);
}

// MFMA edge-message GEMM: msg[e,i] = sum_{c,j} bond[e,c]*neigh[e,j]*We[h,c,i*32+j]
//                                  + sum_j V[h,g(e),i*32+j]*neigh[e,j]
// Block = 256 thr = 4 waves; 128 edges/block; wave: 2 M-tiles x 2 N-tiles of 16x16x32.
// A-frag built in regs: bond scalar (LDS, +33 pad: conflict-free) x lane-resident neigh8.
// B-frag: contiguous 8 bf16 from pre-converted Bh/Vb (single dwordx4).
__global__ __launch_bounds__(256) void msg_mfma(
    const float* __restrict__ atom, const float* __restrict__ bond,
    const unsigned short* __restrict__ Bh, const unsigned short* __restrict__ Vb,
    const int* __restrict__ pair, const int* __restrict__ bg,
    float* __restrict__ agg)
{
    __shared__ float bl[128 * 33];
    __shared__ int gmm[2];
    const int tid = threadIdx.x;
    const int h  = blockIdx.y;
    const int e0 = blockIdx.x * 128;
    for (int x = tid; x < 1024; x += 256) {        // stage bond[e0:e0+128, :]
        int e = x >> 3, c4 = (x & 7) << 2;
        float4 v = *(const float4*)(bond + (size_t)(e0 + e) * 32 + c4);
        float* d = &bl[e * 33 + c4];
        d[0] = v.x; d[1] = v.y; d[2] = v.z; d[3] = v.w;
    }
    if (tid == 0) { gmm[0] = bg[e0]; gmm[1] = bg[e0 + 127]; }

    const int wave = tid >> 6, lane = tid & 63;
    const int ln = lane & 15, quad = lane >> 4;
    const int em0 = e0 + wave * 32 + ln;           // A row (M-tile 0)
    const int em1 = em0 + 16;                      // A row (M-tile 1)
    const int src0 = pair[2 * em0 + 1], src1 = pair[2 * em1 + 1];
    const int gv0 = bg[em0], gv1 = bg[em1];
    float n0[8], n1[8];
    {
        const float* p0 = atom + (size_t)src0 * 32 + quad * 8;
        const float* p1 = atom + (size_t)src1 * 32 + quad * 8;
        float4 a = *(const float4*)p0, b = *(const float4*)(p0 + 4);
        n0[0]=a.x; n0[1]=a.y; n0[2]=a.z; n0[3]=a.w;
        n0[4]=b.x; n0[5]=b.y; n0[6]=b.z; n0[7]=b.w;
        float4 c = *(const float4*)p1, d = *(const float4*)(p1 + 4);
        n1[0]=c.x; n1[1]=c.y; n1[2]=c.z; n1[3]=c.w;
        n1[4]=d.x; n1[5]=d.y; n1[6]=d.z; n1[7]=d.w;
    }
    __syncthreads();
    f4 acc00 = {0,0,0,0}, acc01 = {0,0,0,0}, acc10 = {0,0,0,0}, acc11 = {0,0,0,0};
    const unsigned short* bp = Bh + (size_t)h * 32 * 1024 + ln * 32 + quad * 8;
    const int bo0 = (wave * 32 + ln) * 33;
    const int bo1 = bo0 + 16 * 33;
    #pragma unroll 4
    for (int c = 0; c < 32; ++c) {
        short8 b0 = *(const short8*)(bp + c * 1024);
        short8 b1 = *(const short8*)(bp + c * 1024 + 512);
        float c0 = bl[bo0 + c], c1 = bl[bo1 + c];
        short8 a0, a1;
        #pragma unroll
        for (int q = 0; q < 8; ++q) {
            a0[q] = (short)bfb(c0 * n0[q]);
            a1[q] = (short)bfb(c1 * n1[q]);
        }
        acc00 = __builtin_amdgcn_mfma_f32_16x16x32_bf16(a0, b0, acc00, 0, 0, 0);
        acc01 = __builtin_amdgcn_mfma_f32_16x16x32_bf16(a0, b1, acc01, 0, 0, 0);
        acc10 = __builtin_amdgcn_mfma_f32_16x16x32_bf16(a1, b0, acc10, 0, 0, 0);
        acc11 = __builtin_amdgcn_mfma_f32_16x16x32_bf16(a1, b1, acc11, 0, 0, 0);
    }
    // state/V term: 1-2 extra k-steps (bg sorted -> block spans few graphs)
    short8 nb0, nb1;
    #pragma unroll
    for (int q = 0; q < 8; ++q) { nb0[q] = (short)bfb(n0[q]); nb1[q] = (short)bfb(n1[q]); }
    const short8 zz = {0,0,0,0,0,0,0,0};
    const int gmin = gmm[0], gmax = gmm[1];
    for (int g = gmin; g <= gmax; ++g) {
        const unsigned short* vp = Vb + ((size_t)h * 16 + g) * 1024 + ln * 32 + quad * 8;
        short8 b0 = *(const short8*)vp;
        short8 b1 = *(const short8*)(vp + 512);
        short8 a0 = (gv0 == g) ? nb0 : zz;
        short8 a1 = (gv1 == g) ? nb1 : zz;
        acc00 = __builtin_amdgcn_mfma_f32_16x16x32_bf16(a0, b0, acc00, 0, 0, 0);
        acc01 = __builtin_amdgcn_mfma_f32_16x16x32_bf16(a0, b1, acc01, 0, 0, 0);
        acc10 = __builtin_amdgcn_mfma_f32_16x16x32_bf16(a1, b0, acc10, 0, 0, 0);
        acc11 = __builtin_amdgcn_mfma_f32_16x16x32_bf16(a1, b1, acc11, 0, 0, 0);
    }
    // epilogue: D[row=quad*4+r][col=ln] -> edge = base + quad*4+r, i = nt*16+ln
    #pragma unroll
    for (int r = 0; r < 4; ++r) {
        int eA = e0 + wave * 32 + quad * 4 + r;
        int eB = eA + 16;
        int aA = pair[2 * eA], aB = pair[2 * eB];
        float* dA = agg + ((size_t)h * NA + aA) * 32;
        float* dB = agg + ((size_t)h * NA + aB) * 32;
        atomicAdd(dA + ln,      acc00[r]);
        atomicAdd(dA + 16 + ln, acc01[r]);
        atomicAdd(dB + ln,      acc10[r]);
        atomicAdd(dB + 16 + ln, acc11[r]);
    }
}

// GRU (STEPS=1): qkv[h][a][i]
__global__ __launch_bounds__(256) void gru_kernel(
    const float* __restrict__ atom, const float* __restrict__ agg,
    const float* __restrict__ Wx, const float* __restrict__ Wh,
    const float* __restrict__ bx, const float* __restrict__ bh,
    float* __restrict__ qkv)
{
    __shared__ float ag[8][32], at[8][32];
    const int tid = threadIdx.x;
    const int r = tid >> 5, i = tid & 31;
    const int ha = blockIdx.x * 8 + r;
    const int h = ha >> 13;
    const int a = ha & 8191;
    ag[r][i] = agg[(size_t)ha * 32 + i];
    at[r][i] = atom[(size_t)a * 32 + i];
    __syncthreads();
    const float* wx = Wx + (size_t)h * 32 * 96;
    const float* wh = Wh + (size_t)h * 32 * 96;
    float x0 = bx[h*96 + i], x1 = bx[h*96 + 32 + i], x2 = bx[h*96 + 64 + i];
    float g0 = bh[h*96 + i], g1 = bh[h*96 + 32 + i], g2 = bh[h*96 + 64 + i];
    #pragma unroll 4
    for (int c = 0; c < 32; ++c) {
        float av = ag[r][c], hv = at[r][c];
        x0 += av * wx[c*96 + i]; x1 += av * wx[c*96 + 32 + i]; x2 += av * wx[c*96 + 64 + i];
        g0 += hv * wh[c*96 + i]; g1 += hv * wh[c*96 + 32 + i]; g2 += hv * wh[c*96 + 64 + i];
    }
    float z  = 1.f / (1.f + __expf(-(x0 + g0)));
    float rr = 1.f / (1.f + __expf(-(x1 + g1)));
    float hc = tanhf(x2 + rr * g2);
    float hn = z * at[r][i] + (1.f - z) * hc;
    qkv[(size_t)ha * 32 + i] = hn;
}

// Flash attention phase 1 (f32): thread owns one q row, one k-shard of 512.
__global__ __launch_bounds__(128) void attn_kernel(
    const float* __restrict__ qkv, float* __restrict__ part)
{
    __shared__ float Kt[32][32], Vt[32][32];
    const int tid = threadIdx.x;
    const int q = blockIdx.x * 128 + tid;
    const int sh = blockIdx.y;
    const float* Q  = qkv;
    const float* K  = qkv + (size_t)NA * 32;
    const float* Vv = qkv + (size_t)2 * NA * 32;
    float qr[32];
    #pragma unroll
    for (int w = 0; w < 8; ++w) {
        float4 v = *(const float4*)(Q + (size_t)q * 32 + w * 4);
        qr[w*4] = v.x; qr[w*4+1] = v.y; qr[w*4+2] = v.z; qr[w*4+3] = v.w;
    }
    float m = -INFINITY, l = 0.f;
    float acc[32];
    #pragma unroll
    for (int c = 0; c < 32; ++c) acc[c] = 0.f;
    const float scale = 0.1767766952966369f;
    for (int kt = 0; kt < 512; kt += 32) {
        const int k0 = sh * 512 + kt;
        __syncthreads();
        {
            int x = tid * 8;
            *(float4*)(&Kt[0][0] + x)     = *(const float4*)(K + (size_t)k0 * 32 + x);
            *(float4*)(&Kt[0][0] + x + 4) = *(const float4*)(K + (size_t)k0 * 32 + x + 4);
            *(float4*)(&Vt[0][0] + x)     = *(const float4*)(Vv + (size_t)k0 * 32 + x);
            *(float4*)(&Vt[0][0] + x + 4) = *(const float4*)(Vv + (size_t)k0 * 32 + x + 4);
        }
        __syncthreads();
        float s[32];
        #pragma unroll
        for (int kk = 0; kk < 32; ++kk) {
            float d = 0.f;
            #pragma unroll
            for (int c8 = 0; c8 < 8; ++c8) {
                const float4 kv = *(const float4*)(&Kt[kk][c8 * 4]);
                d += qr[c8*4] * kv.x + qr[c8*4+1] * kv.y + qr[c8*4+2] * kv.z + qr[c8*4+3] * kv.w;
            }
            s[kk] = d * scale;
        }
        float tmax = s[0];
        #pragma unroll
        for (int kk = 1; kk < 32; ++kk) tmax = fmaxf(tmax, s[kk]);
        float mn = fmaxf(m, tmax);
        float al = __expf(m - mn);
        l *= al;
        #pragma unroll
        for (int c = 0; c < 32; ++c) acc[c] *= al;
        #pragma unroll
        for (int kk = 0; kk < 32; ++kk) {
            float p = __expf(s[kk] - mn);
            l += p;
            #pragma unroll
            for (int c8 = 0; c8 < 8; ++c8) {
                const float4 vv = *(const float4*)(&Vt[kk][c8 * 4]);
                acc[c8*4]   += p * vv.x; acc[c8*4+1] += p * vv.y;
                acc[c8*4+2] += p * vv.z; acc[c8*4+3] += p * vv.w;
            }
        }
        m = mn;
    }
    float* pp = part + ((size_t)sh * NA + q) * PART_STRIDE;
    #pragma unroll
    for (int c = 0; c < 32; ++c) pp[c] = acc[c];
    pp[32] = m; pp[33] = l;
}

__global__ __launch_bounds__(256) void merge_kernel(const float* __restrict__ part,
                                                    float* __restrict__ out)
{
    const int tid = threadIdx.x;
    const int r = tid >> 5, c = tid & 31;
    const int q = blockIdx.x * 8 + r;
    float ms = -INFINITY;
    #pragma unroll
    for (int sh = 0; sh < NSHARD; ++sh)
        ms = fmaxf(ms, part[((size_t)sh * NA + q) * PART_STRIDE + 32]);
    float den = 0.f, num = 0.f;
    #pragma unroll
    for (int sh = 0; sh < NSHARD; ++sh) {
        const float* pp = part + ((size_t)sh * NA + q) * PART_STRIDE;
        float w = __expf(pp[32] - ms);
        den += w * pp[33];
        num += w * pp[c];
    }
    out[(size_t)q * 32 + c] = num / den;
}

extern "C" void kernel_launch(void* const* d_in, const int* in_sizes, int n_in,
                              void* d_out, int out_size, void* d_ws, size_t ws_size,
                              hipStream_t stream)
{
    const float* atom  = (const float*)d_in[0];
    const float* bond  = (const float*)d_in[1];
    const float* state = (const float*)d_in[2];
    const float* We    = (const float*)d_in[3];
    const float* be    = (const float*)d_in[4];
    const float* Wx    = (const float*)d_in[5];
    const float* Wh    = (const float*)d_in[6];
    const float* bx    = (const float*)d_in[7];
    const float* bh    = (const float*)d_in[8];
    const int*   pair  = (const int*)d_in[9];
    const int*   bg    = (const int*)d_in[11];
    float* ws   = (float*)d_ws;
    unsigned short* Bh = (unsigned short*)(ws + OFF_BH);
    float* agg  = ws + OFF_AGG;
    float* qkv  = ws + OFF_QKV;
    float* part = ws + OFF_PART;
    unsigned short* Vb = (unsigned short*)(ws + OFF_VB);
    float* out  = (float*)d_out;

    hipMemsetAsync(agg, 0, (size_t)3 * NA * 32 * sizeof(float), stream);
    prep_bh<<<96, 256, 0, stream>>>(We, Bh);
    prep_v<<<48, 256, 0, stream>>>(state, We, be, Vb);
    msg_mfma<<<dim3(NB / 128, 3), 256, 0, stream>>>(atom, bond, Bh, Vb, pair, bg, agg);
    gru_kernel<<<3 * NA / 8, 256, 0, stream>>>(atom, agg, Wx, Wh, bx, bh, qkv);
    attn_kernel<<<dim3(NA / 128, NSHARD), 128, 0, stream>>>(qkv, part);
    merge_kernel<<<NA / 8, 256, 0, stream>>>(part, out);
}

// Round 3
// 260.392 us; speedup vs baseline: 3.4028x; 1.6935x over previous
//
#include <hip/hip_runtime.h>
#include <hip/hip_bf16.h>
#include <math.h>

#define NA 8192
#define NB 131072
#define NG 16
#define NSHARD 16
#define PART_STRIDE 34

// workspace layout (float offsets)
#define OFF_BH   0u          // 3*32*1024 bf16   = 49152 floats
#define OFF_VB   49152u      // 3*16*1024 bf16   = 24576 floats
#define OFF_AGG  73728u      // 3*8192*32 f32    = 786432
#define OFF_QH   860160u     // 8192*32 bf16     = 131072 floats each
#define OFF_QL   991232u
#define OFF_KH   1122304u
#define OFF_KL   1253376u
#define OFF_VTH  1384448u    // transposed [feat][atom]
#define OFF_VTL  1515520u
#define OFF_PART 1646592u    // 16*8192*34 f32   = 4456448  (end 6103040 f ~ 24.4 MB)

typedef __attribute__((ext_vector_type(8))) short short8;
typedef __attribute__((ext_vector_type(4))) float f4;

__device__ inline unsigned short bfb(float x) {
    __hip_bfloat16 b = __float2bfloat16(x);   // RNE
    return reinterpret_cast<unsigned short&>(b);
}
__device__ inline float bf2f(unsigned short u) {
    unsigned int x = ((unsigned int)u) << 16;
    return __uint_as_float(x);
}

// Bh[h][c][n] = bf16(We[h][c][n]), c<32 (bond channels only)
__global__ __launch_bounds__(256) void prep_bh(const float* __restrict__ We,
                                               unsigned short* __restrict__ Bh)
{
    int idx = blockIdx.x * 256 + threadIdx.x;
    int hc = idx >> 8;
    int n4 = (idx & 255) * 4;
    const float4 v = *(const float4*)(We + ((size_t)((hc >> 5) * 64 + (hc & 31))) * 1024 + n4);
    unsigned short* d = Bh + (size_t)hc * 1024 + n4;
    d[0] = bfb(v.x); d[1] = bfb(v.y); d[2] = bfb(v.z); d[3] = bfb(v.w);
}

// Vb[h][g][n] = bf16( sum_c state[g,c]*We[h,32+c,n] + be[h,n] )
__global__ __launch_bounds__(256) void prep_v(const float* __restrict__ state,
    const float* __restrict__ We, const float* __restrict__ be,
    unsigned short* __restrict__ Vb)
{
    int h = blockIdx.x >> 4, g = blockIdx.x & 15;
    const float* st = state + g * 32;
    const float* W  = We + ((size_t)h * 64 + 32) * 1024;
    const float* bb = be + (size_t)h * 1024;
    int n = threadIdx.x * 4;
    float4 acc = *(const float4*)(bb + n);
    for (int c = 0; c < 32; ++c) {
        float s = st[c];
        const float4 w = *(const float4*)(W + c * 1024 + n);
        acc.x += s * w.x; acc.y += s * w.y; acc.z += s * w.z; acc.w += s * w.w;
    }
    unsigned short* d = Vb + ((size_t)h * 16 + g) * 1024 + n;
    d[0] = bfb(acc.x); d[1] = bfb(acc.y); d[2] = bfb(acc.z); d[3] = bfb(acc.w);
}

// MFMA edge-message GEMM + atomic segment-sum (see R2 notes).
__global__ __launch_bounds__(256) void msg_mfma(
    const float* __restrict__ atom, const float* __restrict__ bond,
    const unsigned short* __restrict__ Bh, const unsigned short* __restrict__ Vb,
    const int* __restrict__ pair, const int* __restrict__ bg,
    float* __restrict__ agg)
{
    __shared__ float bl[128 * 33];
    __shared__ int gmm[2];
    const int tid = threadIdx.x;
    const int h  = blockIdx.y;
    const int e0 = blockIdx.x * 128;
    for (int x = tid; x < 1024; x += 256) {
        int e = x >> 3, c4 = (x & 7) << 2;
        float4 v = *(const float4*)(bond + (size_t)(e0 + e) * 32 + c4);
        float* d = &bl[e * 33 + c4];
        d[0] = v.x; d[1] = v.y; d[2] = v.z; d[3] = v.w;
    }
    if (tid == 0) { gmm[0] = bg[e0]; gmm[1] = bg[e0 + 127]; }

    const int wave = tid >> 6, lane = tid & 63;
    const int ln = lane & 15, quad = lane >> 4;
    const int em0 = e0 + wave * 32 + ln;
    const int em1 = em0 + 16;
    const int src0 = pair[2 * em0 + 1], src1 = pair[2 * em1 + 1];
    const int gv0 = bg[em0], gv1 = bg[em1];
    float n0[8], n1[8];
    {
        const float* p0 = atom + (size_t)src0 * 32 + quad * 8;
        const float* p1 = atom + (size_t)src1 * 32 + quad * 8;
        float4 a = *(const float4*)p0, b = *(const float4*)(p0 + 4);
        n0[0]=a.x; n0[1]=a.y; n0[2]=a.z; n0[3]=a.w;
        n0[4]=b.x; n0[5]=b.y; n0[6]=b.z; n0[7]=b.w;
        float4 c = *(const float4*)p1, d = *(const float4*)(p1 + 4);
        n1[0]=c.x; n1[1]=c.y; n1[2]=c.z; n1[3]=c.w;
        n1[4]=d.x; n1[5]=d.y; n1[6]=d.z; n1[7]=d.w;
    }
    __syncthreads();
    f4 acc00 = {0,0,0,0}, acc01 = {0,0,0,0}, acc10 = {0,0,0,0}, acc11 = {0,0,0,0};
    const unsigned short* bp = Bh + (size_t)h * 32 * 1024 + ln * 32 + quad * 8;
    const int bo0 = (wave * 32 + ln) * 33;
    const int bo1 = bo0 + 16 * 33;
    #pragma unroll 4
    for (int c = 0; c < 32; ++c) {
        short8 b0 = *(const short8*)(bp + c * 1024);
        short8 b1 = *(const short8*)(bp + c * 1024 + 512);
        float c0 = bl[bo0 + c], c1 = bl[bo1 + c];
        short8 a0, a1;
        #pragma unroll
        for (int q = 0; q < 8; ++q) {
            a0[q] = (short)bfb(c0 * n0[q]);
            a1[q] = (short)bfb(c1 * n1[q]);
        }
        acc00 = __builtin_amdgcn_mfma_f32_16x16x32_bf16(a0, b0, acc00, 0, 0, 0);
        acc01 = __builtin_amdgcn_mfma_f32_16x16x32_bf16(a0, b1, acc01, 0, 0, 0);
        acc10 = __builtin_amdgcn_mfma_f32_16x16x32_bf16(a1, b0, acc10, 0, 0, 0);
        acc11 = __builtin_amdgcn_mfma_f32_16x16x32_bf16(a1, b1, acc11, 0, 0, 0);
    }
    short8 nb0, nb1;
    #pragma unroll
    for (int q = 0; q < 8; ++q) { nb0[q] = (short)bfb(n0[q]); nb1[q] = (short)bfb(n1[q]); }
    const short8 zz = {0,0,0,0,0,0,0,0};
    const int gmin = gmm[0], gmax = gmm[1];
    for (int g = gmin; g <= gmax; ++g) {
        const unsigned short* vp = Vb + ((size_t)h * 16 + g) * 1024 + ln * 32 + quad * 8;
        short8 b0 = *(const short8*)vp;
        short8 b1 = *(const short8*)(vp + 512);
        short8 a0 = (gv0 == g) ? nb0 : zz;
        short8 a1 = (gv1 == g) ? nb1 : zz;
        acc00 = __builtin_amdgcn_mfma_f32_16x16x32_bf16(a0, b0, acc00, 0, 0, 0);
        acc01 = __builtin_amdgcn_mfma_f32_16x16x32_bf16(a0, b1, acc01, 0, 0, 0);
        acc10 = __builtin_amdgcn_mfma_f32_16x16x32_bf16(a1, b0, acc10, 0, 0, 0);
        acc11 = __builtin_amdgcn_mfma_f32_16x16x32_bf16(a1, b1, acc11, 0, 0, 0);
    }
    #pragma unroll
    for (int r = 0; r < 4; ++r) {
        int eA = e0 + wave * 32 + quad * 4 + r;
        int eB = eA + 16;
        int aA = pair[2 * eA], aB = pair[2 * eB];
        float* dA = agg + ((size_t)h * NA + aA) * 32;
        float* dB = agg + ((size_t)h * NA + aB) * 32;
        atomicAdd(dA + ln,      acc00[r]);
        atomicAdd(dA + 16 + ln, acc01[r]);
        atomicAdd(dB + ln,      acc10[r]);
        atomicAdd(dB + 16 + ln, acc11[r]);
    }
}

// GRU + emit split-bf16 Q (pre-scaled by 1/sqrt(32)), K, and transposed V.
__global__ __launch_bounds__(256) void gru_kernel(
    const float* __restrict__ atom, const float* __restrict__ agg,
    const float* __restrict__ Wx, const float* __restrict__ Wh,
    const float* __restrict__ bx, const float* __restrict__ bh,
    unsigned short* __restrict__ Qh, unsigned short* __restrict__ Ql,
    unsigned short* __restrict__ Kh, unsigned short* __restrict__ Kl,
    unsigned short* __restrict__ Vth, unsigned short* __restrict__ Vtl)
{
    __shared__ float ag[8][33], at[8][33], hb[8][33];
    const int tid = threadIdx.x;
    const int r = tid >> 5, i = tid & 31;
    const int ha = blockIdx.x * 8 + r;
    const int h = ha >> 13;
    const int a = ha & 8191;
    ag[r][i] = agg[(size_t)ha * 32 + i];
    at[r][i] = atom[(size_t)a * 32 + i];
    __syncthreads();
    const float* wx = Wx + (size_t)h * 32 * 96;
    const float* wh = Wh + (size_t)h * 32 * 96;
    float x0 = bx[h*96 + i], x1 = bx[h*96 + 32 + i], x2 = bx[h*96 + 64 + i];
    float g0 = bh[h*96 + i], g1 = bh[h*96 + 32 + i], g2 = bh[h*96 + 64 + i];
    #pragma unroll 4
    for (int c = 0; c < 32; ++c) {
        float av = ag[r][c], hv = at[r][c];
        x0 += av * wx[c*96 + i]; x1 += av * wx[c*96 + 32 + i]; x2 += av * wx[c*96 + 64 + i];
        g0 += hv * wh[c*96 + i]; g1 += hv * wh[c*96 + 32 + i]; g2 += hv * wh[c*96 + 64 + i];
    }
    float z  = 1.f / (1.f + __expf(-(x0 + g0)));
    float rr = 1.f / (1.f + __expf(-(x1 + g1)));
    float hc = tanhf(x2 + rr * g2);
    float hn = z * at[r][i] + (1.f - z) * hc;
    if (h == 0) {
        float x = hn * 0.1767766952966369f;     // fold 1/sqrt(d) into Q
        unsigned short hi = bfb(x);
        Qh[(size_t)a * 32 + i] = hi;
        Ql[(size_t)a * 32 + i] = bfb(x - bf2f(hi));
    } else if (h == 1) {
        unsigned short hi = bfb(hn);
        Kh[(size_t)a * 32 + i] = hi;
        Kl[(size_t)a * 32 + i] = bfb(hn - bf2f(hi));
    } else {
        hb[r][i] = hn;
        __syncthreads();
        const int a0 = blockIdx.x * 8 - 2 * NA;   // base atom for this block
        const int i2 = tid >> 3, a2 = tid & 7;
        float v = hb[a2][i2];
        unsigned short hi = bfb(v);
        Vth[(size_t)i2 * NA + a0 + a2] = hi;
        Vtl[(size_t)i2 * NA + a0 + a2] = bfb(v - bf2f(hi));
    }
}

// MFMA flash attention. Block=256 (4 waves); wave owns 32 q rows (2 tiles of 16),
// iterates its 512-key shard in 32-key chunks. Q/K/V in hi+lo bf16 splits.
__global__ __launch_bounds__(256) void attn_mfma(
    const unsigned short* __restrict__ Qh, const unsigned short* __restrict__ Ql,
    const unsigned short* __restrict__ Kh, const unsigned short* __restrict__ Kl,
    const unsigned short* __restrict__ Vth, const unsigned short* __restrict__ Vtl,
    float* __restrict__ part)
{
    __shared__ unsigned short pb[4][2][16 * 40];   // per-wave P round-trip buffers
    const int tid = threadIdx.x;
    const int wave = tid >> 6, lane = tid & 63;
    const int ln = lane & 15, quad = lane >> 4;
    const int sh = blockIdx.y;
    const int q0 = blockIdx.x * 128 + wave * 32;

    short8 qh0 = *(const short8*)(Qh + (size_t)(q0 + ln) * 32 + quad * 8);
    short8 ql0 = *(const short8*)(Ql + (size_t)(q0 + ln) * 32 + quad * 8);
    short8 qh1 = *(const short8*)(Qh + (size_t)(q0 + 16 + ln) * 32 + quad * 8);
    short8 ql1 = *(const short8*)(Ql + (size_t)(q0 + 16 + ln) * 32 + quad * 8);

    f4 a00 = {0,0,0,0}, a01 = {0,0,0,0}, a10 = {0,0,0,0}, a11 = {0,0,0,0};
    float l0[4] = {0,0,0,0}, l1[4] = {0,0,0,0};
    float m = -INFINITY;
    unsigned short* p0b = &pb[wave][0][0];
    unsigned short* p1b = &pb[wave][1][0];

    const int kbeg = sh * (NA / NSHARD);
    for (int k0 = kbeg; k0 < kbeg + NA / NSHARD; k0 += 32) {
        const size_t ko0 = (size_t)(k0 + ln) * 32 + quad * 8;
        const size_t ko1 = (size_t)(k0 + 16 + ln) * 32 + quad * 8;
        short8 kh0 = *(const short8*)(Kh + ko0);
        short8 kh1 = *(const short8*)(Kh + ko1);
        short8 kl0 = *(const short8*)(Kl + ko0);
        short8 kl1 = *(const short8*)(Kl + ko1);

        f4 s00 = {0,0,0,0}, s01 = {0,0,0,0}, s10 = {0,0,0,0}, s11 = {0,0,0,0};
        s00 = __builtin_amdgcn_mfma_f32_16x16x32_bf16(ql0, kh0, s00, 0, 0, 0);
        s00 = __builtin_amdgcn_mfma_f32_16x16x32_bf16(qh0, kl0, s00, 0, 0, 0);
        s00 = __builtin_amdgcn_mfma_f32_16x16x32_bf16(qh0, kh0, s00, 0, 0, 0);
        s01 = __builtin_amdgcn_mfma_f32_16x16x32_bf16(ql0, kh1, s01, 0, 0, 0);
        s01 = __builtin_amdgcn_mfma_f32_16x16x32_bf16(qh0, kl1, s01, 0, 0, 0);
        s01 = __builtin_amdgcn_mfma_f32_16x16x32_bf16(qh0, kh1, s01, 0, 0, 0);
        s10 = __builtin_amdgcn_mfma_f32_16x16x32_bf16(ql1, kh0, s10, 0, 0, 0);
        s10 = __builtin_amdgcn_mfma_f32_16x16x32_bf16(qh1, kl0, s10, 0, 0, 0);
        s10 = __builtin_amdgcn_mfma_f32_16x16x32_bf16(qh1, kh0, s10, 0, 0, 0);
        s11 = __builtin_amdgcn_mfma_f32_16x16x32_bf16(ql1, kh1, s11, 0, 0, 0);
        s11 = __builtin_amdgcn_mfma_f32_16x16x32_bf16(qh1, kl1, s11, 0, 0, 0);
        s11 = __builtin_amdgcn_mfma_f32_16x16x32_bf16(qh1, kh1, s11, 0, 0, 0);

        // wave-wide tile max (row-uniform upper bound for online softmax)
        float mx = fmaxf(fmaxf(fmaxf(s00[0], s00[1]), fmaxf(s00[2], s00[3])),
                         fmaxf(fmaxf(s01[0], s01[1]), fmaxf(s01[2], s01[3])));
        mx = fmaxf(mx, fmaxf(fmaxf(fmaxf(s10[0], s10[1]), fmaxf(s10[2], s10[3])),
                             fmaxf(fmaxf(s11[0], s11[1]), fmaxf(s11[2], s11[3]))));
        #pragma unroll
        for (int msk = 1; msk < 64; msk <<= 1)
            mx = fmaxf(mx, __shfl_xor(mx, msk));
        const float mn = fmaxf(m, mx);
        const float al = __expf(m - mn);
        m = mn;
        #pragma unroll
        for (int r = 0; r < 4; ++r) {
            a00[r] *= al; a01[r] *= al; a10[r] *= al; a11[r] *= al;
            l0[r] *= al;  l1[r] *= al;
        }
        #pragma unroll
        for (int r = 0; r < 4; ++r) {
            const int row = (quad * 4 + r) * 40;
            float p;
            p = __expf(s00[r] - m); l0[r] += p; p0b[row + ln]      = bfb(p);
            p = __expf(s01[r] - m); l0[r] += p; p0b[row + 16 + ln] = bfb(p);
            p = __expf(s10[r] - m); l1[r] += p; p1b[row + ln]      = bfb(p);
            p = __expf(s11[r] - m); l1[r] += p; p1b[row + 16 + ln] = bfb(p);
        }
        short8 pa0 = *(const short8*)(p0b + ln * 40 + quad * 8);
        short8 pa1 = *(const short8*)(p1b + ln * 40 + quad * 8);

        const size_t vo0 = (size_t)ln * NA + k0 + quad * 8;
        const size_t vo1 = (size_t)(16 + ln) * NA + k0 + quad * 8;
        short8 vh0 = *(const short8*)(Vth + vo0);
        short8 vh1 = *(const short8*)(Vth + vo1);
        short8 vl0 = *(const short8*)(Vtl + vo0);
        short8 vl1 = *(const short8*)(Vtl + vo1);

        a00 = __builtin_amdgcn_mfma_f32_16x16x32_bf16(pa0, vl0, a00, 0, 0, 0);
        a00 = __builtin_amdgcn_mfma_f32_16x16x32_bf16(pa0, vh0, a00, 0, 0, 0);
        a01 = __builtin_amdgcn_mfma_f32_16x16x32_bf16(pa0, vl1, a01, 0, 0, 0);
        a01 = __builtin_amdgcn_mfma_f32_16x16x32_bf16(pa0, vh1, a01, 0, 0, 0);
        a10 = __builtin_amdgcn_mfma_f32_16x16x32_bf16(pa1, vl0, a10, 0, 0, 0);
        a10 = __builtin_amdgcn_mfma_f32_16x16x32_bf16(pa1, vh0, a10, 0, 0, 0);
        a11 = __builtin_amdgcn_mfma_f32_16x16x32_bf16(pa1, vl1, a11, 0, 0, 0);
        a11 = __builtin_amdgcn_mfma_f32_16x16x32_bf16(pa1, vh1, a11, 0, 0, 0);
    }
    // full row sums: cols 0..15 (tile 0) + 16..31 (tile 1) live across 16 lanes
    #pragma unroll
    for (int msk = 1; msk < 16; msk <<= 1) {
        #pragma unroll
        for (int r = 0; r < 4; ++r) {
            l0[r] += __shfl_xor(l0[r], msk);
            l1[r] += __shfl_xor(l1[r], msk);
        }
    }
    #pragma unroll
    for (int r = 0; r < 4; ++r) {
        const int row0 = q0 + quad * 4 + r;
        float* pp = part + ((size_t)sh * NA + row0) * PART_STRIDE;
        pp[ln] = a00[r]; pp[16 + ln] = a01[r];
        if (ln == 0) { pp[32] = m; pp[33] = l0[r]; }
        float* pq = part + ((size_t)sh * NA + row0 + 16) * PART_STRIDE;
        pq[ln] = a10[r]; pq[16 + ln] = a11[r];
        if (ln == 0) { pq[32] = m; pq[33] = l1[r]; }
    }
}

__global__ __launch_bounds__(256) void merge_kernel(const float* __restrict__ part,
                                                    float* __restrict__ out)
{
    const int tid = threadIdx.x;
    const int r = tid >> 5, c = tid & 31;
    const int q = blockIdx.x * 8 + r;
    float ms = -INFINITY;
    #pragma unroll
    for (int sh = 0; sh < NSHARD; ++sh)
        ms = fmaxf(ms, part[((size_t)sh * NA + q) * PART_STRIDE + 32]);
    float den = 0.f, num = 0.f;
    #pragma unroll
    for (int sh = 0; sh < NSHARD; ++sh) {
        const float* pp = part + ((size_t)sh * NA + q) * PART_STRIDE;
        float w = __expf(pp[32] - ms);
        den += w * pp[33];
        num += w * pp[c];
    }
    out[(size_t)q * 32 + c] = num / den;
}

extern "C" void kernel_launch(void* const* d_in, const int* in_sizes, int n_in,
                              void* d_out, int out_size, void* d_ws, size_t ws_size,
                              hipStream_t stream)
{
    const float* atom  = (const float*)d_in[0];
    const float* bond  = (const float*)d_in[1];
    const float* state = (const float*)d_in[2];
    const float* We    = (const float*)d_in[3];
    const float* be    = (const float*)d_in[4];
    const float* Wx    = (const float*)d_in[5];
    const float* Wh    = (const float*)d_in[6];
    const float* bx    = (const float*)d_in[7];
    const float* bh    = (const float*)d_in[8];
    const int*   pair  = (const int*)d_in[9];
    const int*   bg    = (const int*)d_in[11];
    float* ws = (float*)d_ws;
    unsigned short* Bh  = (unsigned short*)(ws + OFF_BH);
    unsigned short* Vb  = (unsigned short*)(ws + OFF_VB);
    float* agg  = ws + OFF_AGG;
    unsigned short* Qh  = (unsigned short*)(ws + OFF_QH);
    unsigned short* Ql  = (unsigned short*)(ws + OFF_QL);
    unsigned short* Kh  = (unsigned short*)(ws + OFF_KH);
    unsigned short* Kl  = (unsigned short*)(ws + OFF_KL);
    unsigned short* Vth = (unsigned short*)(ws + OFF_VTH);
    unsigned short* Vtl = (unsigned short*)(ws + OFF_VTL);
    float* part = ws + OFF_PART;
    float* out  = (float*)d_out;

    hipMemsetAsync(agg, 0, (size_t)3 * NA * 32 * sizeof(float), stream);
    prep_bh<<<96, 256, 0, stream>>>(We, Bh);
    prep_v<<<48, 256, 0, stream>>>(state, We, be, Vb);
    msg_mfma<<<dim3(NB / 128, 3), 256, 0, stream>>>(atom, bond, Bh, Vb, pair, bg, agg);
    gru_kernel<<<3 * NA / 8, 256, 0, stream>>>(atom, agg, Wx, Wh, bx, bh,
                                               Qh, Ql, Kh, Kl, Vth, Vtl);
    attn_mfma<<<dim3(NA / 128, NSHARD), 256, 0, stream>>>(Qh, Ql, Kh, Kl, Vth, Vtl, part);
    merge_kernel<<<NA / 8, 256, 0, stream>>>(part, out);
}

// Round 4
// 252.815 us; speedup vs baseline: 3.5048x; 1.0300x over previous
//
#include <hip/hip_runtime.h>
#include <hip/hip_bf16.h>
#include <math.h>

#define NA 8192
#define NB 131072
#define NG 16
#define NSHARD 16
#define PART_STRIDE 34

// workspace layout (float offsets)
#define OFF_BH   0u          // 3*32*1024 bf16   = 49152 floats
#define OFF_VB   49152u      // 3*16*1024 bf16   = 24576 floats
#define OFF_AGG  73728u      // 3*8192*32 f32    = 786432
#define OFF_QH   860160u     // 8192*32 bf16     = 131072 floats each
#define OFF_QL   991232u
#define OFF_KH   1122304u
#define OFF_KL   1253376u
#define OFF_VTH  1384448u    // transposed [feat][atom]
#define OFF_VTL  1515520u
#define OFF_PART 1646592u    // 16*8192*34 f32   = 4456448  (end 6103040 f ~ 24.4 MB)

typedef __attribute__((ext_vector_type(8))) short short8;
typedef __attribute__((ext_vector_type(4))) float f4;
typedef __attribute__((ext_vector_type(2))) float f2;
typedef __attribute__((ext_vector_type(2))) unsigned int uint2v;

__device__ inline unsigned short bfb(float x) {
    __hip_bfloat16 b = __float2bfloat16(x);   // RNE
    return reinterpret_cast<unsigned short&>(b);
}
__device__ inline float bf2f(unsigned short u) {
    unsigned int x = ((unsigned int)u) << 16;
    return __uint_as_float(x);
}
// packed 2xf32 -> 2xbf16 in one uint (v_cvt_pk_bf16_f32 on gfx950)
__device__ inline unsigned int pk2(float x, float y) {
    __hip_bfloat162 t = __float22bfloat162_rn(make_float2(x, y));
    union { __hip_bfloat162 b; unsigned int u; } cv;
    cv.b = t;
    return cv.u;
}

// Bh[h][c][n] = bf16(We[h][c][n]), c<32 (bond channels only)
__global__ __launch_bounds__(256) void prep_bh(const float* __restrict__ We,
                                               unsigned short* __restrict__ Bh)
{
    int idx = blockIdx.x * 256 + threadIdx.x;
    int hc = idx >> 8;
    int n4 = (idx & 255) * 4;
    const float4 v = *(const float4*)(We + ((size_t)((hc >> 5) * 64 + (hc & 31))) * 1024 + n4);
    unsigned short* d = Bh + (size_t)hc * 1024 + n4;
    d[0] = bfb(v.x); d[1] = bfb(v.y); d[2] = bfb(v.z); d[3] = bfb(v.w);
}

// Vb[h][g][n] = bf16( sum_c state[g,c]*We[h,32+c,n] + be[h,n] )
__global__ __launch_bounds__(256) void prep_v(const float* __restrict__ state,
    const float* __restrict__ We, const float* __restrict__ be,
    unsigned short* __restrict__ Vb)
{
    int h = blockIdx.x >> 4, g = blockIdx.x & 15;
    const float* st = state + g * 32;
    const float* W  = We + ((size_t)h * 64 + 32) * 1024;
    const float* bb = be + (size_t)h * 1024;
    int n = threadIdx.x * 4;
    float4 acc = *(const float4*)(bb + n);
    for (int c = 0; c < 32; ++c) {
        float s = st[c];
        const float4 w = *(const float4*)(W + c * 1024 + n);
        acc.x += s * w.x; acc.y += s * w.y; acc.z += s * w.z; acc.w += s * w.w;
    }
    unsigned short* d = Vb + ((size_t)h * 16 + g) * 1024 + n;
    d[0] = bfb(acc.x); d[1] = bfb(acc.y); d[2] = bfb(acc.z); d[3] = bfb(acc.w);
}

// MFMA edge-message GEMM + atomic segment-sum.
// A-frag build now packed: v_pk_mul_f32 + v_cvt_pk_bf16_f32; bond coeffs via ds_read_b128.
__global__ __launch_bounds__(256) void msg_mfma(
    const float* __restrict__ atom, const float* __restrict__ bond,
    const unsigned short* __restrict__ Bh, const unsigned short* __restrict__ Vb,
    const int* __restrict__ pair, const int* __restrict__ bg,
    float* __restrict__ agg)
{
    __shared__ float bl[128 * 36];     // stride 36: 16B-aligned rows for b128 reads
    __shared__ int gmm[2];
    const int tid = threadIdx.x;
    const int h  = blockIdx.y;
    const int e0 = blockIdx.x * 128;
    for (int x = tid; x < 1024; x += 256) {
        int e = x >> 3, c4 = (x & 7) << 2;
        float4 v = *(const float4*)(bond + (size_t)(e0 + e) * 32 + c4);
        float* d = &bl[e * 36 + c4];
        d[0] = v.x; d[1] = v.y; d[2] = v.z; d[3] = v.w;
    }
    if (tid == 0) { gmm[0] = bg[e0]; gmm[1] = bg[e0 + 127]; }

    const int wave = tid >> 6, lane = tid & 63;
    const int ln = lane & 15, quad = lane >> 4;
    const int em0 = e0 + wave * 32 + ln;
    const int em1 = em0 + 16;
    const int src0 = pair[2 * em0 + 1], src1 = pair[2 * em1 + 1];
    const int gv0 = bg[em0], gv1 = bg[em1];
    f2 n0p[4], n1p[4];
    {
        const float* p0 = atom + (size_t)src0 * 32 + quad * 8;
        const float* p1 = atom + (size_t)src1 * 32 + quad * 8;
        float4 a = *(const float4*)p0, b = *(const float4*)(p0 + 4);
        n0p[0] = f2{a.x, a.y}; n0p[1] = f2{a.z, a.w};
        n0p[2] = f2{b.x, b.y}; n0p[3] = f2{b.z, b.w};
        float4 c = *(const float4*)p1, d = *(const float4*)(p1 + 4);
        n1p[0] = f2{c.x, c.y}; n1p[1] = f2{c.z, c.w};
        n1p[2] = f2{d.x, d.y}; n1p[3] = f2{d.z, d.w};
    }
    __syncthreads();
    f4 acc00 = {0,0,0,0}, acc01 = {0,0,0,0}, acc10 = {0,0,0,0}, acc11 = {0,0,0,0};
    const unsigned short* bp = Bh + (size_t)h * 32 * 1024 + ln * 32 + quad * 8;
    const int bo0 = (wave * 32 + ln) * 36;
    const int bo1 = bo0 + 16 * 36;
    #pragma unroll 2
    for (int c4 = 0; c4 < 32; c4 += 4) {
        f4 cv0 = *(const f4*)&bl[bo0 + c4];    // ds_read_b128: 4 bond coeffs
        f4 cv1 = *(const f4*)&bl[bo1 + c4];
        #pragma unroll
        for (int u = 0; u < 4; ++u) {
            const unsigned short* bpc = bp + (c4 + u) * 1024;
            short8 b0 = *(const short8*)bpc;
            short8 b1 = *(const short8*)(bpc + 512);
            float c0 = cv0[u], c1 = cv1[u];
            union { unsigned int u4[4]; short8 s; } A0, A1;
            #pragma unroll
            for (int q2 = 0; q2 < 4; ++q2) {
                f2 p0 = c0 * n0p[q2];
                f2 p1 = c1 * n1p[q2];
                A0.u4[q2] = pk2(p0.x, p0.y);
                A1.u4[q2] = pk2(p1.x, p1.y);
            }
            acc00 = __builtin_amdgcn_mfma_f32_16x16x32_bf16(A0.s, b0, acc00, 0, 0, 0);
            acc01 = __builtin_amdgcn_mfma_f32_16x16x32_bf16(A0.s, b1, acc01, 0, 0, 0);
            acc10 = __builtin_amdgcn_mfma_f32_16x16x32_bf16(A1.s, b0, acc10, 0, 0, 0);
            acc11 = __builtin_amdgcn_mfma_f32_16x16x32_bf16(A1.s, b1, acc11, 0, 0, 0);
        }
    }
    // state/V term: few extra k-steps (bg sorted)
    union { unsigned int u4[4]; short8 s; } NB0, NB1;
    #pragma unroll
    for (int q2 = 0; q2 < 4; ++q2) {
        NB0.u4[q2] = pk2(n0p[q2].x, n0p[q2].y);
        NB1.u4[q2] = pk2(n1p[q2].x, n1p[q2].y);
    }
    const short8 zz = {0,0,0,0,0,0,0,0};
    const int gmin = gmm[0], gmax = gmm[1];
    for (int g = gmin; g <= gmax; ++g) {
        const unsigned short* vp = Vb + ((size_t)h * 16 + g) * 1024 + ln * 32 + quad * 8;
        short8 b0 = *(const short8*)vp;
        short8 b1 = *(const short8*)(vp + 512);
        short8 a0 = (gv0 == g) ? NB0.s : zz;
        short8 a1 = (gv1 == g) ? NB1.s : zz;
        acc00 = __builtin_amdgcn_mfma_f32_16x16x32_bf16(a0, b0, acc00, 0, 0, 0);
        acc01 = __builtin_amdgcn_mfma_f32_16x16x32_bf16(a0, b1, acc01, 0, 0, 0);
        acc10 = __builtin_amdgcn_mfma_f32_16x16x32_bf16(a1, b0, acc10, 0, 0, 0);
        acc11 = __builtin_amdgcn_mfma_f32_16x16x32_bf16(a1, b1, acc11, 0, 0, 0);
    }
    #pragma unroll
    for (int r = 0; r < 4; ++r) {
        int eA = e0 + wave * 32 + quad * 4 + r;
        int eB = eA + 16;
        int aA = pair[2 * eA], aB = pair[2 * eB];
        float* dA = agg + ((size_t)h * NA + aA) * 32;
        float* dB = agg + ((size_t)h * NA + aB) * 32;
        atomicAdd(dA + ln,      acc00[r]);
        atomicAdd(dA + 16 + ln, acc01[r]);
        atomicAdd(dB + ln,      acc10[r]);
        atomicAdd(dB + 16 + ln, acc11[r]);
    }
}

// GRU + emit split-bf16 Q (pre-scaled by 1/sqrt(32)), K, and transposed V.
__global__ __launch_bounds__(256) void gru_kernel(
    const float* __restrict__ atom, const float* __restrict__ agg,
    const float* __restrict__ Wx, const float* __restrict__ Wh,
    const float* __restrict__ bx, const float* __restrict__ bh,
    unsigned short* __restrict__ Qh, unsigned short* __restrict__ Ql,
    unsigned short* __restrict__ Kh, unsigned short* __restrict__ Kl,
    unsigned short* __restrict__ Vth, unsigned short* __restrict__ Vtl)
{
    __shared__ float ag[8][33], at[8][33], hb[8][33];
    const int tid = threadIdx.x;
    const int r = tid >> 5, i = tid & 31;
    const int ha = blockIdx.x * 8 + r;
    const int h = ha >> 13;
    const int a = ha & 8191;
    ag[r][i] = agg[(size_t)ha * 32 + i];
    at[r][i] = atom[(size_t)a * 32 + i];
    __syncthreads();
    const float* wx = Wx + (size_t)h * 32 * 96;
    const float* wh = Wh + (size_t)h * 32 * 96;
    float x0 = bx[h*96 + i], x1 = bx[h*96 + 32 + i], x2 = bx[h*96 + 64 + i];
    float g0 = bh[h*96 + i], g1 = bh[h*96 + 32 + i], g2 = bh[h*96 + 64 + i];
    #pragma unroll 4
    for (int c = 0; c < 32; ++c) {
        float av = ag[r][c], hv = at[r][c];
        x0 += av * wx[c*96 + i]; x1 += av * wx[c*96 + 32 + i]; x2 += av * wx[c*96 + 64 + i];
        g0 += hv * wh[c*96 + i]; g1 += hv * wh[c*96 + 32 + i]; g2 += hv * wh[c*96 + 64 + i];
    }
    float z  = 1.f / (1.f + __expf(-(x0 + g0)));
    float rr = 1.f / (1.f + __expf(-(x1 + g1)));
    float hc = tanhf(x2 + rr * g2);
    float hn = z * at[r][i] + (1.f - z) * hc;
    if (h == 0) {
        float x = hn * 0.1767766952966369f;     // fold 1/sqrt(d) into Q
        unsigned short hi = bfb(x);
        Qh[(size_t)a * 32 + i] = hi;
        Ql[(size_t)a * 32 + i] = bfb(x - bf2f(hi));
    } else if (h == 1) {
        unsigned short hi = bfb(hn);
        Kh[(size_t)a * 32 + i] = hi;
        Kl[(size_t)a * 32 + i] = bfb(hn - bf2f(hi));
    } else {
        hb[r][i] = hn;
        __syncthreads();
        const int a0 = blockIdx.x * 8 - 2 * NA;
        const int i2 = tid >> 3, a2 = tid & 7;
        float v = hb[a2][i2];
        unsigned short hi = bfb(v);
        Vth[(size_t)i2 * NA + a0 + a2] = hi;
        Vtl[(size_t)i2 * NA + a0 + a2] = bfb(v - bf2f(hi));
    }
}

// MFMA flash attention, S computed TRANSPOSED (A=K, B=Q) so P exits with 4
// consecutive keys per lane: exp -> cvt_pk -> one ds_write_b64 per tile, then
// b128 A-frag reads. Per-wave private P buffer (no barriers).
__global__ __launch_bounds__(256) void attn_mfma(
    const unsigned short* __restrict__ Qh, const unsigned short* __restrict__ Ql,
    const unsigned short* __restrict__ Kh, const unsigned short* __restrict__ Kl,
    const unsigned short* __restrict__ Vth, const unsigned short* __restrict__ Vtl,
    float* __restrict__ part)
{
    __shared__ unsigned short pb[4][32 * 40];   // [wave][query 0..31][key 0..31], stride 40
    const int tid = threadIdx.x;
    const int wave = tid >> 6, lane = tid & 63;
    const int ln = lane & 15, quad = lane >> 4;
    const int sh = blockIdx.y;
    const int q0 = blockIdx.x * 128 + wave * 32;

    short8 qh0 = *(const short8*)(Qh + (size_t)(q0 + ln) * 32 + quad * 8);
    short8 ql0 = *(const short8*)(Ql + (size_t)(q0 + ln) * 32 + quad * 8);
    short8 qh1 = *(const short8*)(Qh + (size_t)(q0 + 16 + ln) * 32 + quad * 8);
    short8 ql1 = *(const short8*)(Ql + (size_t)(q0 + 16 + ln) * 32 + quad * 8);

    f4 a00 = {0,0,0,0}, a01 = {0,0,0,0}, a10 = {0,0,0,0}, a11 = {0,0,0,0};
    float l0 = 0.f, l1 = 0.f;
    float m = -INFINITY;
    unsigned short* pw = &pb[wave][0];

    const int kbeg = sh * (NA / NSHARD);
    for (int k0 = kbeg; k0 < kbeg + NA / NSHARD; k0 += 32) {
        const size_t ko0 = (size_t)(k0 + ln) * 32 + quad * 8;
        const size_t ko1 = (size_t)(k0 + 16 + ln) * 32 + quad * 8;
        short8 kh0 = *(const short8*)(Kh + ko0);
        short8 kh1 = *(const short8*)(Kh + ko1);
        short8 kl0 = *(const short8*)(Kl + ko0);
        short8 kl1 = *(const short8*)(Kl + ko1);

        // S^T[kt][qt]: rows = keys, cols = queries
        f4 s00 = {0,0,0,0}, s01 = {0,0,0,0}, s10 = {0,0,0,0}, s11 = {0,0,0,0};
        s00 = __builtin_amdgcn_mfma_f32_16x16x32_bf16(kl0, qh0, s00, 0, 0, 0);
        s00 = __builtin_amdgcn_mfma_f32_16x16x32_bf16(kh0, ql0, s00, 0, 0, 0);
        s00 = __builtin_amdgcn_mfma_f32_16x16x32_bf16(kh0, qh0, s00, 0, 0, 0);
        s01 = __builtin_amdgcn_mfma_f32_16x16x32_bf16(kl0, qh1, s01, 0, 0, 0);
        s01 = __builtin_amdgcn_mfma_f32_16x16x32_bf16(kh0, ql1, s01, 0, 0, 0);
        s01 = __builtin_amdgcn_mfma_f32_16x16x32_bf16(kh0, qh1, s01, 0, 0, 0);
        s10 = __builtin_amdgcn_mfma_f32_16x16x32_bf16(kl1, qh0, s10, 0, 0, 0);
        s10 = __builtin_amdgcn_mfma_f32_16x16x32_bf16(kh1, ql0, s10, 0, 0, 0);
        s10 = __builtin_amdgcn_mfma_f32_16x16x32_bf16(kh1, qh0, s10, 0, 0, 0);
        s11 = __builtin_amdgcn_mfma_f32_16x16x32_bf16(kl1, qh1, s11, 0, 0, 0);
        s11 = __builtin_amdgcn_mfma_f32_16x16x32_bf16(kh1, ql1, s11, 0, 0, 0);
        s11 = __builtin_amdgcn_mfma_f32_16x16x32_bf16(kh1, qh1, s11, 0, 0, 0);

        float mx = fmaxf(fmaxf(fmaxf(s00[0], s00[1]), fmaxf(s00[2], s00[3])),
                         fmaxf(fmaxf(s01[0], s01[1]), fmaxf(s01[2], s01[3])));
        mx = fmaxf(mx, fmaxf(fmaxf(fmaxf(s10[0], s10[1]), fmaxf(s10[2], s10[3])),
                             fmaxf(fmaxf(s11[0], s11[1]), fmaxf(s11[2], s11[3]))));
        #pragma unroll
        for (int msk = 1; msk < 64; msk <<= 1)
            mx = fmaxf(mx, __shfl_xor(mx, msk));
        const float mn = fmaxf(m, mx);
        const float al = __expf(m - mn);
        m = mn;
        #pragma unroll
        for (int r = 0; r < 4; ++r) {
            a00[r] *= al; a01[r] *= al; a10[r] *= al; a11[r] *= al;
        }
        l0 *= al; l1 *= al;

        // exp + packed P writes: lane holds 4 consecutive keys (kt*16+quad*4+r), query qt*16+ln
        {
            float e0 = __expf(s00[0]-m), e1 = __expf(s00[1]-m),
                  e2 = __expf(s00[2]-m), e3 = __expf(s00[3]-m);
            l0 += (e0+e1)+(e2+e3);
            *(uint2v*)&pw[ln*40 + quad*4] = uint2v{pk2(e0,e1), pk2(e2,e3)};
            e0 = __expf(s10[0]-m); e1 = __expf(s10[1]-m);
            e2 = __expf(s10[2]-m); e3 = __expf(s10[3]-m);
            l0 += (e0+e1)+(e2+e3);
            *(uint2v*)&pw[ln*40 + 16 + quad*4] = uint2v{pk2(e0,e1), pk2(e2,e3)};
            e0 = __expf(s01[0]-m); e1 = __expf(s01[1]-m);
            e2 = __expf(s01[2]-m); e3 = __expf(s01[3]-m);
            l1 += (e0+e1)+(e2+e3);
            *(uint2v*)&pw[(16+ln)*40 + quad*4] = uint2v{pk2(e0,e1), pk2(e2,e3)};
            e0 = __expf(s11[0]-m); e1 = __expf(s11[1]-m);
            e2 = __expf(s11[2]-m); e3 = __expf(s11[3]-m);
            l1 += (e0+e1)+(e2+e3);
            *(uint2v*)&pw[(16+ln)*40 + 16 + quad*4] = uint2v{pk2(e0,e1), pk2(e2,e3)};
        }
        short8 pa0 = *(const short8*)&pw[ln*40 + quad*8];
        short8 pa1 = *(const short8*)&pw[(16+ln)*40 + quad*8];

        const size_t vo0 = (size_t)ln * NA + k0 + quad * 8;
        const size_t vo1 = (size_t)(16 + ln) * NA + k0 + quad * 8;
        short8 vh0 = *(const short8*)(Vth + vo0);
        short8 vh1 = *(const short8*)(Vth + vo1);
        short8 vl0 = *(const short8*)(Vtl + vo0);
        short8 vl1 = *(const short8*)(Vtl + vo1);

        a00 = __builtin_amdgcn_mfma_f32_16x16x32_bf16(pa0, vl0, a00, 0, 0, 0);
        a00 = __builtin_amdgcn_mfma_f32_16x16x32_bf16(pa0, vh0, a00, 0, 0, 0);
        a01 = __builtin_amdgcn_mfma_f32_16x16x32_bf16(pa0, vl1, a01, 0, 0, 0);
        a01 = __builtin_amdgcn_mfma_f32_16x16x32_bf16(pa0, vh1, a01, 0, 0, 0);
        a10 = __builtin_amdgcn_mfma_f32_16x16x32_bf16(pa1, vl0, a10, 0, 0, 0);
        a10 = __builtin_amdgcn_mfma_f32_16x16x32_bf16(pa1, vh0, a10, 0, 0, 0);
        a11 = __builtin_amdgcn_mfma_f32_16x16x32_bf16(pa1, vl1, a11, 0, 0, 0);
        a11 = __builtin_amdgcn_mfma_f32_16x16x32_bf16(pa1, vh1, a11, 0, 0, 0);
    }
    // l: per-lane column partials -> full sums (replicated across quads)
    l0 += __shfl_xor(l0, 16); l0 += __shfl_xor(l0, 32);
    l1 += __shfl_xor(l1, 16); l1 += __shfl_xor(l1, 32);

    #pragma unroll
    for (int r = 0; r < 4; ++r) {
        const int row0 = q0 + quad * 4 + r;
        float* pp = part + ((size_t)sh * NA + row0) * PART_STRIDE;
        pp[ln] = a00[r]; pp[16 + ln] = a01[r];
        float* pq = part + ((size_t)sh * NA + row0 + 16) * PART_STRIDE;
        pq[ln] = a10[r]; pq[16 + ln] = a11[r];
    }
    if (quad == 0) {
        float* pp = part + ((size_t)sh * NA + q0 + ln) * PART_STRIDE;
        pp[32] = m; pp[33] = l0;
        float* pq = part + ((size_t)sh * NA + q0 + 16 + ln) * PART_STRIDE;
        pq[32] = m; pq[33] = l1;
    }
}

__global__ __launch_bounds__(256) void merge_kernel(const float* __restrict__ part,
                                                    float* __restrict__ out)
{
    const int tid = threadIdx.x;
    const int r = tid >> 5, c = tid & 31;
    const int q = blockIdx.x * 8 + r;
    float ms = -INFINITY;
    #pragma unroll
    for (int sh = 0; sh < NSHARD; ++sh)
        ms = fmaxf(ms, part[((size_t)sh * NA + q) * PART_STRIDE + 32]);
    float den = 0.f, num = 0.f;
    #pragma unroll
    for (int sh = 0; sh < NSHARD; ++sh) {
        const float* pp = part + ((size_t)sh * NA + q) * PART_STRIDE;
        float w = __expf(pp[32] - ms);
        den += w * pp[33];
        num += w * pp[c];
    }
    out[(size_t)q * 32 + c] = num / den;
}

extern "C" void kernel_launch(void* const* d_in, const int* in_sizes, int n_in,
                              void* d_out, int out_size, void* d_ws, size_t ws_size,
                              hipStream_t stream)
{
    const float* atom  = (const float*)d_in[0];
    const float* bond  = (const float*)d_in[1];
    const float* state = (const float*)d_in[2];
    const float* We    = (const float*)d_in[3];
    const float* be    = (const float*)d_in[4];
    const float* Wx    = (const float*)d_in[5];
    const float* Wh    = (const float*)d_in[6];
    const float* bx    = (const float*)d_in[7];
    const float* bh    = (const float*)d_in[8];
    const int*   pair  = (const int*)d_in[9];
    const int*   bg    = (const int*)d_in[11];
    float* ws = (float*)d_ws;
    unsigned short* Bh  = (unsigned short*)(ws + OFF_BH);
    unsigned short* Vb  = (unsigned short*)(ws + OFF_VB);
    float* agg  = ws + OFF_AGG;
    unsigned short* Qh  = (unsigned short*)(ws + OFF_QH);
    unsigned short* Ql  = (unsigned short*)(ws + OFF_QL);
    unsigned short* Kh  = (unsigned short*)(ws + OFF_KH);
    unsigned short* Kl  = (unsigned short*)(ws + OFF_KL);
    unsigned short* Vth = (unsigned short*)(ws + OFF_VTH);
    unsigned short* Vtl = (unsigned short*)(ws + OFF_VTL);
    float* part = ws + OFF_PART;
    float* out  = (float*)d_out;

    hipMemsetAsync(agg, 0, (size_t)3 * NA * 32 * sizeof(float), stream);
    prep_bh<<<96, 256, 0, stream>>>(We, Bh);
    prep_v<<<48, 256, 0, stream>>>(state, We, be, Vb);
    msg_mfma<<<dim3(NB / 128, 3), 256, 0, stream>>>(atom, bond, Bh, Vb, pair, bg, agg);
    gru_kernel<<<3 * NA / 8, 256, 0, stream>>>(atom, agg, Wx, Wh, bx, bh,
                                               Qh, Ql, Kh, Kl, Vth, Vtl);
    attn_mfma<<<dim3(NA / 128, NSHARD), 256, 0, stream>>>(Qh, Ql, Kh, Kl, Vth, Vtl, part);
    merge_kernel<<<NA / 8, 256, 0, stream>>>(part, out);
}